// Round 4
// baseline (173.268 us; speedup 1.0000x reference)
//
#include <hip/hip_runtime.h>
#include <hip/hip_bf16.h>

#define BATCH  4096
#define NUM_GO 30000
#define DIM    128

#define BM      256       // rows per block: 8 waves x 2 row-tiles x 16
#define THREADS 512
constexpr int NCHUNKS = (NUM_GO + 63) / 64;          // 469 (last: 3 subtiles)
constexpr int NGO_PAD = NCHUNKS * 64;                // 30016
constexpr int NFRAGP  = (NGO_PAD / 16) * 4 * 64;     // 480256 16B fragments
#define CHUNK_BYTES 16384                             // 64 go x 128 dim x 2B
#define MBS     3776                                  // packed-bit row stride (bytes)
#define NGRP    32                                    // chunk-groups
#define NBLK    (16 * NGRP)                           // 512 = 2 blocks/CU, persistent

typedef __bf16 bf16x8 __attribute__((ext_vector_type(8)));
typedef float  f32x4  __attribute__((ext_vector_type(4)));

__device__ inline short f2bf(float x) {
    __hip_bfloat16 b = __float2bfloat16(x);
    return __builtin_bit_cast(short, b);
}

__device__ __forceinline__ void gload_lds16(const void* g, void* l) {
    __builtin_amdgcn_global_load_lds(
        (const __attribute__((address_space(1))) void*)g,
        (__attribute__((address_space(3))) void*)l, 16, 0, 0);
}

// P: f32 -> bf16 linear
__global__ __launch_bounds__(256) void cvt_bf16(const float* __restrict__ src,
                                                short* __restrict__ dst, int n4) {
    int i = blockIdx.x * blockDim.x + threadIdx.x;
    if (i >= n4) return;
    float4 v = ((const float4*)src)[i];
    short4 o = make_short4(f2bf(v.x), f2bf(v.y), f2bf(v.z), f2bf(v.w));
    ((short4*)dst)[i] = o;
}

// F: f32 -> bf16 packed in MFMA-fragment order, zero-padded to NGO_PAD rows.
__global__ __launch_bounds__(256) void cvt_F_packed(const float* __restrict__ F,
                                                    short* __restrict__ Fp) {
    int t = blockIdx.x * 256 + threadIdx.x;
    if (t >= NFRAGP) return;
    int lcol = t & 15, lrow = (t >> 4) & 3, ks = (t >> 6) & 3, g = t >> 8;
    int row = g * 16 + lcol;
    union { short s[8]; int4 v; } u;
    if (row < NUM_GO) {
        const float* src = F + (size_t)row * DIM + ks * 32 + lrow * 8;
#pragma unroll
        for (int i = 0; i < 8; ++i) u.s[i] = f2bf(src[i]);
    } else {
        u.v = make_int4(0, 0, 0, 0);
    }
    *(int4*)(Fp + (size_t)t * 8) = u.v;
}

// ---- mask bit-compress: one block per row, LINEAR 117KB stream per block ----
// Consecutive blocks read consecutive 120KB rows -> chip-wide near-linear walk
// (the canonical pattern that achieves ~6.3-6.6 TB/s). Output: bit b of byte
// (c>>3) = mask[row][c]; 32:1 compression, 15.5 MB total.
__global__ __launch_bounds__(256) void compress_mask(const int* __restrict__ mask,
                                                     unsigned char* __restrict__ mb) {
    const int row  = blockIdx.x;
    const int tid  = threadIdx.x;
    const int lane = tid & 63;
    const int4* src = (const int4*)(mask + (size_t)row * NUM_GO);   // 7500 int4
    unsigned char* dst = mb + (size_t)row * MBS;

#pragma unroll 1
    for (int base = 0; base < 8192; base += 2048) {   // 4 macro-iters, 8-deep MLP
        int4 mv[8];
#pragma unroll
        for (int j = 0; j < 8; ++j) {
            int i4 = base + j * 256 + tid;
            mv[j] = (i4 < 7500) ? src[i4] : make_int4(0, 0, 0, 0);
        }
#pragma unroll
        for (int j = 0; j < 8; ++j) {
            int i4 = base + j * 256 + tid;
            unsigned nib = (unsigned)(mv[j].x | (mv[j].y << 1) |
                                      (mv[j].z << 2) | (mv[j].w << 3));
            unsigned oth = (unsigned)__shfl_xor((int)nib, 1);
            if (!(lane & 1) && i4 < 7500)        // even lanes: 32B contiguous run
                dst[i4 >> 1] = (unsigned char)((nib | (oth << 4)) & 0xFF);
        }
    }
    if (tid < 26) dst[3750 + tid] = 0;   // zero pad cols 30000..30207 region
}

// One 64-go chunk; F from LDS, mask bits from a register u64 per row-tile.
// Swapped MFMA mfma(F,P): lane (lcol,lrow), reg i holds
// logits[r = r0 + lcol][go = chunk*64 + t*16 + lrow*4 + i]  -> bit index
// within the chunk's u64 word is exactly t*16 + lrow*4 + i.
template<int NT>
__device__ __forceinline__ void chunk_compute(
    const short* __restrict__ flds,
    unsigned long long wv0, unsigned long long wv1,
    const bf16x8 a0[4], const bf16x8 a1[4],
    int lane, int lrow, float s2,
    float& sum0, float& pos0, float& sum1, float& pos1)
{
#pragma unroll
    for (int t = 0; t < NT; ++t) {
        bf16x8 f[4];
#pragma unroll
        for (int ks = 0; ks < 4; ++ks)
            f[ks] = *(const bf16x8*)(flds + (t * 256 + ks * 64 + lane) * 8);
        unsigned b0 = (unsigned)(wv0 >> (t * 16 + lrow * 4)) & 0xFu;
        unsigned b1 = (unsigned)(wv1 >> (t * 16 + lrow * 4)) & 0xFu;
        f32x4 acc0 = {0.f, 0.f, 0.f, 0.f};
        f32x4 acc1 = {0.f, 0.f, 0.f, 0.f};
#pragma unroll
        for (int ks = 0; ks < 4; ++ks) {
            acc0 = __builtin_amdgcn_mfma_f32_16x16x32_bf16(f[ks], a0[ks], acc0, 0, 0, 0);
            acc1 = __builtin_amdgcn_mfma_f32_16x16x32_bf16(f[ks], a1[ks], acc1, 0, 0, 0);
        }
#pragma unroll
        for (int i = 0; i < 4; ++i) {
            float e0 = __builtin_amdgcn_exp2f(fmaf(acc0[i], s2, -s2));
            float e1 = __builtin_amdgcn_exp2f(fmaf(acc1[i], s2, -s2));
            float w0 = (float)((b0 >> i) & 1u);
            float w1 = (float)((b1 >> i) & 1u);
            sum0 += e0; pos0 = fmaf(w0, e0, pos0);
            sum1 += e1; pos1 = fmaf(w1, e1, pos1);
        }
    }
}

__global__ __launch_bounds__(THREADS, 4) void infonce_main(
    const short* __restrict__ Pb,   // [BATCH][DIM] bf16
    const short* __restrict__ Fp,   // packed F fragments (padded)
    const unsigned char* __restrict__ mb,  // packed mask bits [BATCH][MBS]
    const float* __restrict__ temp,
    float* __restrict__ rowsum,     // [BATCH] accum (zeroed)
    float* __restrict__ possum)     // [BATCH] accum (zeroed)
{
    __shared__ short flds[2][CHUNK_BYTES / 2];        // 32 KB (F double buffer)
    // 2 blocks/CU (VGPR-capped), grid 512 = fully resident (persistent)

    // decode: XCD x gets 4 whole chunk-groups (16 bx-blocks each) -> F L2 reuse
    const int bid = blockIdx.x;
    const int x   = bid & 7;
    const int rr  = bid >> 3;           // 0..63
    const int g   = x * 4 + (rr >> 4);  // chunk-group 0..31
    const int bx  = rr & 15;            // row-block 0..15

    // chunks [k0, k0+nk): groups 0..20 get 15 chunks, 21..31 get 14 (469 total)
    const int k0 = g * 14 + (g < 21 ? g : 21);
    const int nk = 14 + (g < 21 ? 1 : 0);

    const int tid  = threadIdx.x;
    const int w    = tid >> 6;
    const int lane = tid & 63;
    const int lcol = lane & 15;
    const int lrow = lane >> 4;

    const int r0 = bx * BM + w * 32 + lcol;
    const int r1 = r0 + 16;

    const float s2 = __expf(-temp[0]) * 1.44269504088896f;  // (1/exp(T))*log2e

    bf16x8 a0[4], a1[4];
#pragma unroll
    for (int ks = 0; ks < 4; ++ks) {
        a0[ks] = *(const bf16x8*)(Pb + (size_t)r0 * DIM + ks * 32 + lrow * 8);
        a1[ks] = *(const bf16x8*)(Pb + (size_t)r1 * DIM + ks * 32 + lrow * 8);
    }

    const unsigned char* mrow0 = mb + (size_t)r0 * MBS;
    const unsigned char* mrow1 = mb + (size_t)r1 * MBS;

    // prologue: stage chunk k0
    {
        const char* gbase = (const char*)Fp + (size_t)k0 * CHUNK_BYTES;
        for (int off = w * 1024; off < CHUNK_BYTES; off += 8 * 1024)
            gload_lds16(gbase + off + lane * 16, (char*)flds[0] + off);
    }
    __syncthreads();

    float sum0 = 0.f, pos0 = 0.f, sum1 = 0.f, pos1 = 0.f;

    for (int i = 0; i < nk; ++i) {
        const int cur = i & 1, nxt = cur ^ 1;
        if (i + 1 < nk) {
            const char* gbase = (const char*)Fp + (size_t)(k0 + i + 1) * CHUNK_BYTES;
            for (int off = w * 1024; off < CHUNK_BYTES; off += 8 * 1024)
                gload_lds16(gbase + off + lane * 16, (char*)flds[nxt] + off);
        }
        __builtin_amdgcn_sched_barrier(0);   // keep prefetch issue above compute

        const unsigned long long wv0 =
            *(const unsigned long long*)(mrow0 + (k0 + i) * 8);
        const unsigned long long wv1 =
            *(const unsigned long long*)(mrow1 + (k0 + i) * 8);

        if (k0 + i == NCHUNKS - 1)
            chunk_compute<3>(flds[cur], wv0, wv1, a0, a1, lane, lrow, s2,
                             sum0, pos0, sum1, pos1);
        else
            chunk_compute<4>(flds[cur], wv0, wv1, a0, a1, lane, lrow, s2,
                             sum0, pos0, sum1, pos1);
        __syncthreads();   // drains gload_lds for nxt; flds[nxt] valid next iter
    }

    // combine the 4 lrow replicas of each row's partials, 1 atomic per row per block
    sum0 += __shfl_xor(sum0, 16); sum0 += __shfl_xor(sum0, 32);
    pos0 += __shfl_xor(pos0, 16); pos0 += __shfl_xor(pos0, 32);
    sum1 += __shfl_xor(sum1, 16); sum1 += __shfl_xor(sum1, 32);
    pos1 += __shfl_xor(pos1, 16); pos1 += __shfl_xor(pos1, 32);
    if (lane < 16) {
        atomicAdd(&rowsum[r0], sum0);
        atomicAdd(&possum[r0], pos0);
        atomicAdd(&rowsum[r1], sum1);
        atomicAdd(&possum[r1], pos1);
    }
}

__global__ __launch_bounds__(256) void infonce_finalize(
    const float* __restrict__ rowsum, const float* __restrict__ possum,
    float* __restrict__ out)
{
    float acc = 0.f;
    for (int r = threadIdx.x; r < BATCH; r += 256) {
        float p = possum[r], sm = rowsum[r];
        if (p > 0.f) acc += -logf(p / sm + 1e-8f);   // has_pos <=> pos_sum > 0
    }
    __shared__ float red[4];
#pragma unroll
    for (int off = 32; off >= 1; off >>= 1) acc += __shfl_down(acc, off);
    if ((threadIdx.x & 63) == 0) red[threadIdx.x >> 6] = acc;
    __syncthreads();
    if (threadIdx.x == 0)
        out[0] = (red[0] + red[1] + red[2] + red[3]) * (1.0f / BATCH);
}

extern "C" void kernel_launch(void* const* d_in, const int* in_sizes, int n_in,
                              void* d_out, int out_size, void* d_ws, size_t ws_size,
                              hipStream_t stream) {
    const float* P    = (const float*)d_in[0];
    const float* F    = (const float*)d_in[1];
    const int*   mask = (const int*)d_in[2];
    const float* temp = (const float*)d_in[3];
    float* out = (float*)d_out;

    // ws: rowsum | possum | P_bf16 (1MB) | F_packed (7.7MB) | mask_bits (15.5MB)
    char* ws = (char*)d_ws;
    float* rowsum = (float*)ws;
    float* possum = (float*)(ws + 16384);
    short* Pb     = (short*)(ws + 32768);
    short* Fp     = (short*)(ws + 32768 + (size_t)BATCH * DIM * 2);
    unsigned char* mb = (unsigned char*)(ws + 32768 + (size_t)BATCH * DIM * 2
                                         + (size_t)NFRAGP * 16);

    hipMemsetAsync(rowsum, 0, 32768, stream);

    compress_mask<<<BATCH, 256, 0, stream>>>(mask, mb);

    int nP4 = BATCH * DIM / 4;
    cvt_bf16<<<(nP4 + 255) / 256, 256, 0, stream>>>(P, Pb, nP4);
    cvt_F_packed<<<(NFRAGP + 255) / 256, 256, 0, stream>>>(F, Fp);

    infonce_main<<<NBLK, THREADS, 0, stream>>>(Pb, Fp, mb, temp,
                                               rowsum, possum);
    infonce_finalize<<<1, 256, 0, stream>>>(rowsum, possum, out);
}

// Round 5
// 132.183 us; speedup vs baseline: 1.3108x; 1.3108x over previous
//
#include <hip/hip_runtime.h>
#include <hip/hip_bf16.h>

#define BATCH  4096
#define NUM_GO 30000
#define DIM    128

#define BM      256       // rows per block: 8 waves x 2 row-tiles x 16
#define THREADS 512
#define CPS     2         // 64-GO chunks per block
constexpr int NCHUNKS = (NUM_GO + 63) / 64;          // 469 (last: 3 subtiles)
constexpr int NSEG    = (NCHUNKS + CPS - 1) / CPS;   // 235 (last seg: 1 chunk)
constexpr int NGO_PAD = NCHUNKS * 64;                // 30016
constexpr int NFRAGP  = (NGO_PAD / 16) * 4 * 64;     // 480256 16B fragments
#define CHUNK_BYTES 16384                             // 64 go x 128 dim x 2B
#define NBLK    ((BATCH / BM) * NSEG)                 // 3760 = 8 x 470
#define MSTRIDE 68                                    // packed-mask row stride (bytes)

typedef __bf16 bf16x8 __attribute__((ext_vector_type(8)));
typedef float  f32x4  __attribute__((ext_vector_type(4)));
typedef int    i32x4  __attribute__((ext_vector_type(4)));

__device__ inline short f2bf(float x) {
    __hip_bfloat16 b = __float2bfloat16(x);
    return __builtin_bit_cast(short, b);
}

__device__ __forceinline__ void gload_lds16(const void* g, void* l) {
    __builtin_amdgcn_global_load_lds(
        (const __attribute__((address_space(1))) void*)g,
        (__attribute__((address_space(3))) void*)l, 16, 0, 0);
}

// mask values are exactly {0,1}: pack 4 ints -> 4 bytes of one u32
__device__ __forceinline__ unsigned pack01(i32x4 m) {
    return (unsigned)(m[0] | (m[1] << 8) | (m[2] << 16) | (m[3] << 24));
}

// P: f32 -> bf16 linear
__global__ __launch_bounds__(256) void cvt_bf16(const float* __restrict__ src,
                                                short* __restrict__ dst, int n4) {
    int i = blockIdx.x * blockDim.x + threadIdx.x;
    if (i >= n4) return;
    float4 v = ((const float4*)src)[i];
    short4 o = make_short4(f2bf(v.x), f2bf(v.y), f2bf(v.z), f2bf(v.w));
    ((short4*)dst)[i] = o;
}

// F: f32 -> bf16 packed in MFMA-fragment order, zero-padded to NGO_PAD rows.
__global__ __launch_bounds__(256) void cvt_F_packed(const float* __restrict__ F,
                                                    short* __restrict__ Fp) {
    int t = blockIdx.x * 256 + threadIdx.x;
    if (t >= NFRAGP) return;
    int lcol = t & 15, lrow = (t >> 4) & 3, ks = (t >> 6) & 3, g = t >> 8;
    int row = g * 16 + lcol;
    union { short s[8]; int4 v; } u;
    if (row < NUM_GO) {
        const float* src = F + (size_t)row * DIM + ks * 32 + lrow * 8;
#pragma unroll
        for (int i = 0; i < 8; ++i) u.s[i] = f2bf(src[i]);
    } else {
        u.v = make_int4(0, 0, 0, 0);
    }
    *(int4*)(Fp + (size_t)t * 8) = u.v;
}

// One 64-go chunk (NT 16-wide subtiles); F and packed mask both from LDS.
// Swapped MFMA mfma(F,P): lane (lcol,lrow), reg i holds
// logits[r = r0 + lcol][go = chunk*64 + t*16 + lrow*4 + i].
template<int NT>
__device__ __forceinline__ void chunk_compute(
    const short* __restrict__ flds, const unsigned char* __restrict__ mrow,
    int k, const bf16x8 a0[4], const bf16x8 a1[4],
    int w, int lane, int lcol, int lrow, float s2,
    float& sum0, float& pos0, float& sum1, float& pos1)
{
#pragma unroll
    for (int t = 0; t < NT; ++t) {
        bf16x8 f[4];
#pragma unroll
        for (int ks = 0; ks < 4; ++ks)
            f[ks] = *(const bf16x8*)(flds + k * (CHUNK_BYTES / 2)
                                          + (t * 256 + ks * 64 + lane) * 8);
        const unsigned pk0 = *(const unsigned*)(mrow + (w * 32 + lcol) * MSTRIDE
                                                     + t * 16 + lrow * 4);
        const unsigned pk1 = *(const unsigned*)(mrow + (w * 32 + 16 + lcol) * MSTRIDE
                                                     + t * 16 + lrow * 4);
        f32x4 acc0 = {0.f, 0.f, 0.f, 0.f};
        f32x4 acc1 = {0.f, 0.f, 0.f, 0.f};
#pragma unroll
        for (int ks = 0; ks < 4; ++ks) {
            acc0 = __builtin_amdgcn_mfma_f32_16x16x32_bf16(f[ks], a0[ks], acc0, 0, 0, 0);
            acc1 = __builtin_amdgcn_mfma_f32_16x16x32_bf16(f[ks], a1[ks], acc1, 0, 0, 0);
        }
#pragma unroll
        for (int i = 0; i < 4; ++i) {
            float e0 = __builtin_amdgcn_exp2f(fmaf(acc0[i], s2, -s2));
            float e1 = __builtin_amdgcn_exp2f(fmaf(acc1[i], s2, -s2));
            float w0 = (float)((pk0 >> (8 * i)) & 0xFFu);   // v_cvt_f32_ubyte
            float w1 = (float)((pk1 >> (8 * i)) & 0xFFu);
            sum0 += e0; pos0 = fmaf(w0, e0, pos0);
            sum1 += e1; pos1 = fmaf(w1, e1, pos1);
        }
    }
}

__global__ __launch_bounds__(THREADS, 4) void infonce_main(
    const short* __restrict__ Pb,   // [BATCH][DIM] bf16
    const short* __restrict__ Fp,   // packed F fragments (padded)
    const int*  __restrict__ mask,  // [BATCH][NUM_GO]
    const float* __restrict__ temp,
    float* __restrict__ rowsum,     // [BATCH] accum (zeroed)
    float* __restrict__ possum)     // [BATCH] accum (zeroed)
{
    __shared__ short flds[CPS * CHUNK_BYTES / 2];          // 32 KB
    __shared__ unsigned char mpk[CPS][256 * MSTRIDE];      // 2 x 17 KB
    // total ~66 KB -> 2 blocks/CU

    // bijective XCD-aware decode: blocks of the same GO segment -> same XCD
    const int bid = blockIdx.x;
    const int wid = (bid & 7) * (NBLK / 8) + (bid >> 3);
    const int by  = wid >> 4;       // GO segment 0..234
    const int bx  = wid & 15;       // row-block 0..15

    const int tid  = threadIdx.x;
    const int w    = tid >> 6;
    const int lane = tid & 63;
    const int lcol = lane & 15;
    const int lrow = lane >> 4;

    const int r0 = bx * BM + w * 32 + lcol;
    const int r1 = r0 + 16;

    const int c0 = by * CPS;
    const int nc = (c0 + CPS <= NCHUNKS) ? CPS : (NCHUNKS - c0);   // 2 or 1

    const float s2 = __expf(-temp[0]) * 1.44269504088896f;  // (1/exp(T))*log2e

    bf16x8 a0[4], a1[4];
#pragma unroll
    for (int ks = 0; ks < 4; ++ks) {
        a0[ks] = *(const bf16x8*)(Pb + (size_t)r0 * DIM + ks * 32 + lrow * 8);
        a1[ks] = *(const bf16x8*)(Pb + (size_t)r1 * DIM + ks * 32 + lrow * 8);
    }

    // ---- cooperative contiguous mask staging ----
    // Per wave-instruction: 32 lanes read 512B of ONE row (2 rows/instr).
    // NON-TEMPORAL: the mask stream has zero reuse; nt bypasses L2/L3
    // allocation so the 492MB stream stops thrashing the caches.
    {
        const int colb = (lane & 31) * 4;            // 0..124 (col within 2 chunks)
        int col = c0 * 64 + colb;
        if (col > NUM_GO - 4) col = NUM_GO - 4;      // tail-safe, dup reads ok
        const int k    = colb >> 6;                  // which chunk buffer
        const int i16  = (colb >> 2) & 15;           // 16B-slot within chunk row
        const int rb   = w * 2 + (lane >> 5);        // local row base
        const int* gp  = mask + (size_t)(bx * BM + rb) * NUM_GO + col;

        i32x4 mv[16];
#pragma unroll
        for (int j = 0; j < 16; ++j)
            mv[j] = __builtin_nontemporal_load(
                        (const i32x4*)(gp + (size_t)16 * j * NUM_GO));

        // F staging issued after mask loads (counted vmcnt keeps order cheap)
        const int nbytes = nc * CHUNK_BYTES;
        const char* gbase = (const char*)Fp + (size_t)c0 * CHUNK_BYTES;
        for (int off = w * 1024; off < nbytes; off += 8 * 1024)
            gload_lds16(gbase + off + lane * 16, (char*)flds + off);

#pragma unroll
        for (int j = 0; j < 16; ++j)
            *(unsigned*)&mpk[k][(rb + 16 * j) * MSTRIDE + i16 * 4] = pack01(mv[j]);
    }
    __syncthreads();   // single barrier; compute below has zero global traffic

    float sum0 = 0.f, pos0 = 0.f, sum1 = 0.f, pos1 = 0.f;

    // chunk 468 (the only NT=3 one) is alone in segment 234 -> nc==1 there
    if (nc == 2) {
        chunk_compute<4>(flds, mpk[0], 0, a0, a1, w, lane, lcol, lrow, s2,
                         sum0, pos0, sum1, pos1);
        chunk_compute<4>(flds, mpk[1], 1, a0, a1, w, lane, lcol, lrow, s2,
                         sum0, pos0, sum1, pos1);
    } else {
        chunk_compute<3>(flds, mpk[0], 0, a0, a1, w, lane, lcol, lrow, s2,
                         sum0, pos0, sum1, pos1);
    }

    // combine the 4 lrow replicas of each row's partials, 1 atomic per row
    sum0 += __shfl_xor(sum0, 16); sum0 += __shfl_xor(sum0, 32);
    pos0 += __shfl_xor(pos0, 16); pos0 += __shfl_xor(pos0, 32);
    sum1 += __shfl_xor(sum1, 16); sum1 += __shfl_xor(sum1, 32);
    pos1 += __shfl_xor(pos1, 16); pos1 += __shfl_xor(pos1, 32);
    if (lane < 16) {
        atomicAdd(&rowsum[r0], sum0);
        atomicAdd(&possum[r0], pos0);
        atomicAdd(&rowsum[r1], sum1);
        atomicAdd(&possum[r1], pos1);
    }
}

__global__ __launch_bounds__(256) void infonce_finalize(
    const float* __restrict__ rowsum, const float* __restrict__ possum,
    float* __restrict__ out)
{
    float acc = 0.f;
    for (int r = threadIdx.x; r < BATCH; r += 256) {
        float p = possum[r], sm = rowsum[r];
        if (p > 0.f) acc += -logf(p / sm + 1e-8f);   // has_pos <=> pos_sum > 0
    }
    __shared__ float red[4];
#pragma unroll
    for (int off = 32; off >= 1; off >>= 1) acc += __shfl_down(acc, off);
    if ((threadIdx.x & 63) == 0) red[threadIdx.x >> 6] = acc;
    __syncthreads();
    if (threadIdx.x == 0)
        out[0] = (red[0] + red[1] + red[2] + red[3]) * (1.0f / BATCH);
}

extern "C" void kernel_launch(void* const* d_in, const int* in_sizes, int n_in,
                              void* d_out, int out_size, void* d_ws, size_t ws_size,
                              hipStream_t stream) {
    const float* P    = (const float*)d_in[0];
    const float* F    = (const float*)d_in[1];
    const int*   mask = (const int*)d_in[2];
    const float* temp = (const float*)d_in[3];
    float* out = (float*)d_out;

    // ws: rowsum[4096] | possum[4096] | P_bf16 (1 MB) | F_packed (~7.7 MB)
    char* ws = (char*)d_ws;
    float* rowsum = (float*)ws;
    float* possum = (float*)(ws + 16384);
    short* Pb     = (short*)(ws + 32768);
    short* Fp     = (short*)(ws + 32768 + (size_t)BATCH * DIM * 2);

    hipMemsetAsync(rowsum, 0, 32768, stream);

    int nP4 = BATCH * DIM / 4;
    cvt_bf16<<<(nP4 + 255) / 256, 256, 0, stream>>>(P, Pb, nP4);
    cvt_F_packed<<<(NFRAGP + 255) / 256, 256, 0, stream>>>(F, Fp);

    infonce_main<<<NBLK, THREADS, 0, stream>>>(Pb, Fp, mask, temp,
                                               rowsum, possum);
    infonce_finalize<<<1, 256, 0, stream>>>(rowsum, possum, out);
}